// Round 1
// baseline (560.960 us; speedup 1.0000x reference)
//
#include <hip/hip_runtime.h>
#include <stdint.h>

#define Bb 4
#define Tt 2048
#define Dd 1024
#define Hh 16
#define HDd 64
#define Mm 8192   // Bb*Tt

typedef __attribute__((ext_vector_type(8))) short bf16x8;
typedef __attribute__((ext_vector_type(4))) float f32x4;

#define MFMA(a, b, c) __builtin_amdgcn_mfma_f32_16x16x32_bf16(a, b, c, 0, 0, 0)

__device__ __forceinline__ unsigned short f2b(float f) {
  union { float f; uint32_t u; } v; v.f = f;
  return (unsigned short)((v.u + 0x7FFFu + ((v.u >> 16) & 1u)) >> 16);
}

__device__ __forceinline__ void gload_lds16(const void* g, void* l) {
  __builtin_amdgcn_global_load_lds(
      (const __attribute__((address_space(1))) void*)g,
      (__attribute__((address_space(3))) void*)l, 16, 0, 0);
}

// ---------------- x f32 -> bf16 ----------------
__global__ __launch_bounds__(256) void k_convert_x(const float* __restrict__ x,
                                                   unsigned short* __restrict__ xb) {
  int i = (blockIdx.x * 256 + threadIdx.x) * 8;
  float4 a = *(const float4*)(x + i);
  float4 b = *(const float4*)(x + i + 4);
  uint4 o;
  o.x = f2b(a.x) | ((uint32_t)f2b(a.y) << 16);
  o.y = f2b(a.z) | ((uint32_t)f2b(a.w) << 16);
  o.z = f2b(b.x) | ((uint32_t)f2b(b.y) << 16);
  o.w = f2b(b.z) | ((uint32_t)f2b(b.w) << 16);
  *(uint4*)(xb + i) = o;
}

// ---------------- W [K][N] f32 -> Wt [N][K] bf16 ----------------
__global__ __launch_bounds__(256) void k_transpose_w(
    const float* __restrict__ Wk, const float* __restrict__ Wq,
    const float* __restrict__ Wv, const float* __restrict__ Wp,
    unsigned short* __restrict__ WkT, unsigned short* __restrict__ WqT,
    unsigned short* __restrict__ WvT, unsigned short* __restrict__ WpT) {
  const float* W; unsigned short* O;
  int wsel = blockIdx.y;
  W = wsel == 0 ? Wk : wsel == 1 ? Wq : wsel == 2 ? Wv : Wp;
  O = wsel == 0 ? WkT : wsel == 1 ? WqT : wsel == 2 ? WvT : WpT;
  __shared__ unsigned short tile[32][36];
  int kb = (blockIdx.x >> 5) << 5;
  int nb = (blockIdx.x & 31) << 5;
  int t = threadIdx.x;
  int r = t >> 3, c4 = (t & 7) << 2;
  float4 v = *(const float4*)(W + (size_t)(kb + r) * Dd + nb + c4);
  tile[r][c4 + 0] = f2b(v.x); tile[r][c4 + 1] = f2b(v.y);
  tile[r][c4 + 2] = f2b(v.z); tile[r][c4 + 3] = f2b(v.w);
  __syncthreads();
  uint2 o;
  o.x = tile[c4 + 0][r] | ((uint32_t)tile[c4 + 1][r] << 16);
  o.y = tile[c4 + 2][r] | ((uint32_t)tile[c4 + 3][r] << 16);
  *(uint2*)(O + (size_t)(nb + r) * Dd + kb + c4) = o;
}

// ---------------- GEMM: A[M][1024] bf16 @ Bt[N][1024]^T + bias ----------------
// qkv=1: grid(64,24), widx=by>>3 selects {Q,K,V}; Q,K -> [B,H,T,64], V -> [B,H,64,T]
// qkv=0: grid(64,8), f32 out [M][1024]
__global__ __launch_bounds__(256) void k_gemm(
    const unsigned short* __restrict__ A,
    const unsigned short* __restrict__ Bt0, const unsigned short* __restrict__ Bt1,
    const unsigned short* __restrict__ Bt2,
    const float* __restrict__ bias0, const float* __restrict__ bias1,
    const float* __restrict__ bias2,
    unsigned short* __restrict__ Qb, unsigned short* __restrict__ Kb,
    unsigned short* __restrict__ VTb, float* __restrict__ Pout, int qkv) {
  __shared__ __align__(16) unsigned short Al[128 * 32];
  __shared__ __align__(16) unsigned short Bl[128 * 32];
  int tid = threadIdx.x;
  int lane = tid & 63, wid = tid >> 6;
  int wr = wid >> 1, wc = wid & 1;
  int lq = lane & 15, lh = lane >> 4;
  int mb = blockIdx.x * 128;
  int by = blockIdx.y;
  int widx, nb;
  const unsigned short* Bt; const float* bias;
  if (qkv) {
    widx = by >> 3; nb = (by & 7) << 7;
    Bt = widx == 0 ? Bt0 : (widx == 1 ? Bt1 : Bt2);
    bias = widx == 0 ? bias0 : (widx == 1 ? bias1 : bias2);
  } else {
    widx = 3; nb = by << 7; Bt = Bt0; bias = bias0;
  }

  // staging: each wave fills rows [32*wid, 32*wid+32) of both tiles via 2 loads each
  int srow = (wid << 5) + (lane >> 2);
  int scol = (lane & 3) << 3;
  const unsigned short* Ag = A + (size_t)(mb + srow) * Dd + scol;
  const unsigned short* Bg = Bt + (size_t)(nb + srow) * Dd + scol;
  unsigned short* Alw = Al + (wid << 10);  // wid*32 rows * 32 elems (wave-uniform)
  unsigned short* Blw = Bl + (wid << 10);

  f32x4 zero = {0.f, 0.f, 0.f, 0.f};
  f32x4 acc[4][4];
#pragma unroll
  for (int m = 0; m < 4; m++)
#pragma unroll
    for (int n = 0; n < 4; n++) acc[m][n] = zero;

  for (int kb = 0; kb < Dd; kb += 32) {
    __syncthreads();
    gload_lds16(Ag + kb, Alw);
    gload_lds16(Ag + kb + 16 * Dd, Alw + 16 * 32);
    gload_lds16(Bg + kb, Blw);
    gload_lds16(Bg + kb + 16 * Dd, Blw + 16 * 32);
    __syncthreads();
    bf16x8 af[4], bf[4];
#pragma unroll
    for (int m = 0; m < 4; m++)
      af[m] = *(const bf16x8*)(Al + (((wr << 6) + (m << 4) + lq) << 5) + (lh << 3));
#pragma unroll
    for (int n = 0; n < 4; n++)
      bf[n] = *(const bf16x8*)(Bl + (((wc << 6) + (n << 4) + lq) << 5) + (lh << 3));
#pragma unroll
    for (int m = 0; m < 4; m++)
#pragma unroll
      for (int n = 0; n < 4; n++) acc[m][n] = MFMA(af[m], bf[n], acc[m][n]);
  }

  int b_idx = mb >> 11;  // batch index (block-uniform; 128-row tile never crosses T)
#pragma unroll
  for (int n = 0; n < 4; n++) {
    int col = nb + (wc << 6) + (n << 4) + lq;  // 0..1023
    float bb = bias[col];
    int hh = col >> 6, hd = col & 63;
#pragma unroll
    for (int m = 0; m < 4; m++) {
      int row0 = mb + (wr << 6) + (m << 4) + (lh << 2);
      int t0 = row0 & 2047;
      if (widx == 3) {
#pragma unroll
        for (int r = 0; r < 4; r++)
          Pout[(size_t)(row0 + r) * Dd + col] = acc[m][n][r] + bb;
      } else if (widx == 2) {
        float v0 = acc[m][n][0] + bb, v1 = acc[m][n][1] + bb;
        float v2 = acc[m][n][2] + bb, v3 = acc[m][n][3] + bb;
        uint2 pv;
        pv.x = f2b(v0) | ((uint32_t)f2b(v1) << 16);
        pv.y = f2b(v2) | ((uint32_t)f2b(v3) << 16);
        *(uint2*)(VTb + ((size_t)(b_idx * 16 + hh) * 64 + hd) * Tt + t0) = pv;
      } else {
        unsigned short* O = (widx == 0) ? Qb : Kb;
        float s = (widx == 0) ? 0.125f : 1.0f;  // fold 1/sqrt(HD) into Q
#pragma unroll
        for (int r = 0; r < 4; r++) {
          float v = (acc[m][n][r] + bb) * s;
          O[((size_t)(b_idx * 16 + hh) * Tt + (t0 + r)) * 64 + hd] = f2b(v);
        }
      }
    }
  }
}

// ---------------- flash attention (causal), Q pre-scaled ----------------
// block = 4 waves x 16 q-rows = 64 q rows; KV tiles of 64; no max-subtraction
__global__ __launch_bounds__(256) void k_attn(
    const unsigned short* __restrict__ Qb, const unsigned short* __restrict__ Kb,
    const unsigned short* __restrict__ VTb, unsigned short* __restrict__ yb) {
  __shared__ __align__(16) unsigned short Pl[4][16 * 72];
  int blk = blockIdx.x;
  int bh = blk >> 5, qt = blk & 31;
  int tid = threadIdx.x, lane = tid & 63, w = tid >> 6;
  int lq = lane & 15, lh = lane >> 4;
  const unsigned short* Qh = Qb + (size_t)bh * Tt * 64;
  const unsigned short* Kh = Kb + (size_t)bh * Tt * 64;
  const unsigned short* Vh = VTb + (size_t)bh * 64 * Tt;
  unsigned short* Pw = &Pl[w][0];

  int q0 = (qt << 6) + (w << 4);
  bf16x8 aQ0 = *(const bf16x8*)(Qh + (size_t)(q0 + lq) * 64 + (lh << 3));
  bf16x8 aQ1 = *(const bf16x8*)(Qh + (size_t)(q0 + lq) * 64 + 32 + (lh << 3));

  f32x4 zero = {0.f, 0.f, 0.f, 0.f};
  f32x4 O[4];
  float lsum[4] = {0.f, 0.f, 0.f, 0.f};
#pragma unroll
  for (int n = 0; n < 4; n++) O[n] = zero;

  for (int t = 0; t <= qt; ++t) {
    int kv0 = t << 6;
    f32x4 S[4];
#pragma unroll
    for (int n = 0; n < 4; n++) {
      const unsigned short* kp = Kh + (size_t)(kv0 + (n << 4) + lq) * 64 + (lh << 3);
      bf16x8 bk0 = *(const bf16x8*)(kp);
      bf16x8 bk1 = *(const bf16x8*)(kp + 32);
      f32x4 s = zero;
      s = MFMA(aQ0, bk0, s);
      s = MFMA(aQ1, bk1, s);
      S[n] = s;
    }
    if (t == qt) {  // causal mask on diagonal tile
#pragma unroll
      for (int n = 0; n < 4; n++)
#pragma unroll
        for (int r = 0; r < 4; r++)
          if ((n << 4) + lq > (w << 4) + (lh << 2) + r) S[n][r] = -1e30f;
    }
    // P = exp(S); per-lane partial row sums (final reduce after loop)
#pragma unroll
    for (int n = 0; n < 4; n++) {
#pragma unroll
      for (int r = 0; r < 4; r++) {
        float p = __expf(S[n][r]);
        lsum[r] += p;
        Pw[((lh << 2) + r) * 72 + (n << 4) + lq] = f2b(p);
      }
    }
    asm volatile("" ::: "memory");
    bf16x8 aP0 = *(const bf16x8*)(Pw + lq * 72 + (lh << 3));
    bf16x8 aP1 = *(const bf16x8*)(Pw + lq * 72 + 32 + (lh << 3));
#pragma unroll
    for (int n = 0; n < 4; n++) {
      const unsigned short* vp = Vh + (size_t)((n << 4) + lq) * Tt + kv0 + (lh << 3);
      bf16x8 bv0 = *(const bf16x8*)(vp);
      bf16x8 bv1 = *(const bf16x8*)(vp + 32);
      O[n] = MFMA(aP0, bv0, O[n]);
      O[n] = MFMA(aP1, bv1, O[n]);
    }
  }
#pragma unroll
  for (int r = 0; r < 4; r++) {
    float s = lsum[r];
    s += __shfl_xor(s, 1);
    s += __shfl_xor(s, 2);
    s += __shfl_xor(s, 4);
    s += __shfl_xor(s, 8);
    lsum[r] = 1.0f / s;
  }
  int bb = bh >> 4, hh = bh & 15;
#pragma unroll
  for (int n = 0; n < 4; n++) {
    int col = (hh << 6) + (n << 4) + lq;
#pragma unroll
    for (int r = 0; r < 4; r++) {
      int qg = q0 + (lh << 2) + r;
      yb[((size_t)bb * Tt + qg) * Dd + col] = f2b(O[n][r] * lsum[r]);
    }
  }
}

extern "C" void kernel_launch(void* const* d_in, const int* in_sizes, int n_in,
                              void* d_out, int out_size, void* d_ws, size_t ws_size,
                              hipStream_t stream) {
  const float* x = (const float*)d_in[0];
  const float* Wk = (const float*)d_in[1];
  const float* bk = (const float*)d_in[2];
  const float* Wq = (const float*)d_in[3];
  const float* bq = (const float*)d_in[4];
  const float* Wv = (const float*)d_in[5];
  const float* bv = (const float*)d_in[6];
  const float* Wp = (const float*)d_in[7];
  const float* bp = (const float*)d_in[8];
  float* out = (float*)d_out;

  char* ws = (char*)d_ws;
  unsigned short* xb  = (unsigned short*)(ws);                       // 16MB
  unsigned short* WkT = (unsigned short*)(ws + (16ull << 20));       // 2MB each
  unsigned short* WqT = (unsigned short*)(ws + (18ull << 20));
  unsigned short* WvT = (unsigned short*)(ws + (20ull << 20));
  unsigned short* WpT = (unsigned short*)(ws + (22ull << 20));
  unsigned short* Qb  = (unsigned short*)(ws + (24ull << 20));       // 16MB
  unsigned short* Kb  = (unsigned short*)(ws + (40ull << 20));       // 16MB
  unsigned short* VTb = (unsigned short*)(ws + (56ull << 20));       // 16MB
  unsigned short* yb  = (unsigned short*)(ws + (72ull << 20));       // 16MB (ends 88MB)

  k_convert_x<<<4096, 256, 0, stream>>>(x, xb);
  k_transpose_w<<<dim3(1024, 4), 256, 0, stream>>>(Wk, Wq, Wv, Wp, WkT, WqT, WvT, WpT);
  k_gemm<<<dim3(64, 24), 256, 0, stream>>>(xb, WqT, WkT, WvT, bq, bk, bv,
                                           Qb, Kb, VTb, nullptr, 1);
  k_attn<<<2048, 256, 0, stream>>>(Qb, Kb, VTb, yb);
  k_gemm<<<dim3(64, 8), 256, 0, stream>>>(yb, WpT, nullptr, nullptr, bp, nullptr, nullptr,
                                          nullptr, nullptr, nullptr, out, 0);
}

// Round 2
// 460.385 us; speedup vs baseline: 1.2185x; 1.2185x over previous
//
#include <hip/hip_runtime.h>
#include <stdint.h>

#define Bb 4
#define Tt 2048
#define Dd 1024
#define Hh 16
#define HDd 64
#define Mm 8192   // Bb*Tt

typedef __attribute__((ext_vector_type(8))) short bf16x8;
typedef __attribute__((ext_vector_type(4))) float f32x4;

#define MFMA(a, b, c) __builtin_amdgcn_mfma_f32_16x16x32_bf16(a, b, c, 0, 0, 0)

__device__ __forceinline__ unsigned short f2b(float f) {
  union { float f; uint32_t u; } v; v.f = f;
  return (unsigned short)((v.u + 0x7FFFu + ((v.u >> 16) & 1u)) >> 16);
}

__device__ __forceinline__ void gload_lds16(const void* g, void* l) {
  __builtin_amdgcn_global_load_lds(
      (const __attribute__((address_space(1))) void*)g,
      (__attribute__((address_space(3))) void*)l, 16, 0, 0);
}

// ---------------- x f32 -> bf16 ----------------
__global__ __launch_bounds__(256) void k_convert_x(const float* __restrict__ x,
                                                   unsigned short* __restrict__ xb) {
  int i = (blockIdx.x * 256 + threadIdx.x) * 8;
  float4 a = *(const float4*)(x + i);
  float4 b = *(const float4*)(x + i + 4);
  uint4 o;
  o.x = f2b(a.x) | ((uint32_t)f2b(a.y) << 16);
  o.y = f2b(a.z) | ((uint32_t)f2b(a.w) << 16);
  o.z = f2b(b.x) | ((uint32_t)f2b(b.y) << 16);
  o.w = f2b(b.z) | ((uint32_t)f2b(b.w) << 16);
  *(uint4*)(xb + i) = o;
}

// ---------------- W [K][N] f32 -> Wt [N][K] bf16 ----------------
__global__ __launch_bounds__(256) void k_transpose_w(
    const float* __restrict__ Wk, const float* __restrict__ Wq,
    const float* __restrict__ Wv, const float* __restrict__ Wp,
    unsigned short* __restrict__ WkT, unsigned short* __restrict__ WqT,
    unsigned short* __restrict__ WvT, unsigned short* __restrict__ WpT) {
  const float* W; unsigned short* O;
  int wsel = blockIdx.y;
  W = wsel == 0 ? Wk : wsel == 1 ? Wq : wsel == 2 ? Wv : Wp;
  O = wsel == 0 ? WkT : wsel == 1 ? WqT : wsel == 2 ? WvT : WpT;
  __shared__ unsigned short tile[32][36];
  int kb = (blockIdx.x >> 5) << 5;
  int nb = (blockIdx.x & 31) << 5;
  int t = threadIdx.x;
  int r = t >> 3, c4 = (t & 7) << 2;
  float4 v = *(const float4*)(W + (size_t)(kb + r) * Dd + nb + c4);
  tile[r][c4 + 0] = f2b(v.x); tile[r][c4 + 1] = f2b(v.y);
  tile[r][c4 + 2] = f2b(v.z); tile[r][c4 + 3] = f2b(v.w);
  __syncthreads();
  uint2 o;
  o.x = tile[c4 + 0][r] | ((uint32_t)tile[c4 + 1][r] << 16);
  o.y = tile[c4 + 2][r] | ((uint32_t)tile[c4 + 3][r] << 16);
  *(uint2*)(O + (size_t)(nb + r) * Dd + kb + c4) = o;
}

// ---------------- GEMM: A[M][1024] bf16 @ Bt[N][1024]^T + bias ----------------
__global__ __launch_bounds__(256) void k_gemm(
    const unsigned short* __restrict__ A,
    const unsigned short* __restrict__ Bt0, const unsigned short* __restrict__ Bt1,
    const unsigned short* __restrict__ Bt2,
    const float* __restrict__ bias0, const float* __restrict__ bias1,
    const float* __restrict__ bias2,
    unsigned short* __restrict__ Qb, unsigned short* __restrict__ Kb,
    unsigned short* __restrict__ VTb, float* __restrict__ Pout, int qkv) {
  __shared__ __align__(16) unsigned short Al[128 * 32];
  __shared__ __align__(16) unsigned short Bl[128 * 32];
  int tid = threadIdx.x;
  int lane = tid & 63, wid = tid >> 6;
  int wr = wid >> 1, wc = wid & 1;
  int lq = lane & 15, lh = lane >> 4;
  int mb = blockIdx.x * 128;
  int by = blockIdx.y;
  int widx, nb;
  const unsigned short* Bt; const float* bias;
  if (qkv) {
    widx = by >> 3; nb = (by & 7) << 7;
    Bt = widx == 0 ? Bt0 : (widx == 1 ? Bt1 : Bt2);
    bias = widx == 0 ? bias0 : (widx == 1 ? bias1 : bias2);
  } else {
    widx = 3; nb = by << 7; Bt = Bt0; bias = bias0;
  }

  int srow = (wid << 5) + (lane >> 2);
  int scol = (lane & 3) << 3;
  const unsigned short* Ag = A + (size_t)(mb + srow) * Dd + scol;
  const unsigned short* Bg = Bt + (size_t)(nb + srow) * Dd + scol;
  unsigned short* Alw = Al + (wid << 10);
  unsigned short* Blw = Bl + (wid << 10);

  f32x4 zero = {0.f, 0.f, 0.f, 0.f};
  f32x4 acc[4][4];
#pragma unroll
  for (int m = 0; m < 4; m++)
#pragma unroll
    for (int n = 0; n < 4; n++) acc[m][n] = zero;

  for (int kb = 0; kb < Dd; kb += 32) {
    __syncthreads();
    gload_lds16(Ag + kb, Alw);
    gload_lds16(Ag + kb + 16 * Dd, Alw + 16 * 32);
    gload_lds16(Bg + kb, Blw);
    gload_lds16(Bg + kb + 16 * Dd, Blw + 16 * 32);
    __syncthreads();
    bf16x8 af[4], bf[4];
#pragma unroll
    for (int m = 0; m < 4; m++)
      af[m] = *(const bf16x8*)(Al + (((wr << 6) + (m << 4) + lq) << 5) + (lh << 3));
#pragma unroll
    for (int n = 0; n < 4; n++)
      bf[n] = *(const bf16x8*)(Bl + (((wc << 6) + (n << 4) + lq) << 5) + (lh << 3));
#pragma unroll
    for (int m = 0; m < 4; m++)
#pragma unroll
      for (int n = 0; n < 4; n++) acc[m][n] = MFMA(af[m], bf[n], acc[m][n]);
  }

  int b_idx = mb >> 11;
#pragma unroll
  for (int n = 0; n < 4; n++) {
    int col = nb + (wc << 6) + (n << 4) + lq;
    float bb = bias[col];
    int hh = col >> 6, hd = col & 63;
#pragma unroll
    for (int m = 0; m < 4; m++) {
      int row0 = mb + (wr << 6) + (m << 4) + (lh << 2);
      int t0 = row0 & 2047;
      if (widx == 3) {
#pragma unroll
        for (int r = 0; r < 4; r++)
          Pout[(size_t)(row0 + r) * Dd + col] = acc[m][n][r] + bb;
      } else if (widx == 2) {
        float v0 = acc[m][n][0] + bb, v1 = acc[m][n][1] + bb;
        float v2 = acc[m][n][2] + bb, v3 = acc[m][n][3] + bb;
        uint2 pv;
        pv.x = f2b(v0) | ((uint32_t)f2b(v1) << 16);
        pv.y = f2b(v2) | ((uint32_t)f2b(v3) << 16);
        *(uint2*)(VTb + ((size_t)(b_idx * 16 + hh) * 64 + hd) * Tt + t0) = pv;
      } else {
        unsigned short* O = (widx == 0) ? Qb : Kb;
        float s = (widx == 0) ? 0.125f : 1.0f;
#pragma unroll
        for (int r = 0; r < 4; r++) {
          float v = (acc[m][n][r] + bb) * s;
          O[((size_t)(b_idx * 16 + hh) * Tt + (t0 + r)) * 64 + hd] = f2b(v);
        }
      }
    }
  }
}

// ---------------- flash attention (causal), Q pre-scaled ----------------
// block = 4 waves; each wave computes the FULL 64x64 output for a KV subset
// (tiles t = w, w+4, ...). No-max softmax => partial (O, lsum) are additive;
// combined once per block via LDS atomics.
__global__ __launch_bounds__(256) void k_attn(
    const unsigned short* __restrict__ Qb, const unsigned short* __restrict__ Kb,
    const unsigned short* __restrict__ VTb, unsigned short* __restrict__ yb) {
  __shared__ __align__(16) unsigned short Pl[4][64 * 72];  // 36.9 KB; reused as f32 Of[64][65]+Ls[64]
  int blk = blockIdx.x;
  int bh = blk >> 5, qt = blk & 31;
  int tid = threadIdx.x, lane = tid & 63, w = tid >> 6;
  int lq = lane & 15, lh = lane >> 4;
  const unsigned short* __restrict__ Qh = Qb + (size_t)bh * Tt * 64;
  const unsigned short* __restrict__ Kh = Kb + (size_t)bh * Tt * 64;
  const unsigned short* __restrict__ Vh = VTb + (size_t)bh * 64 * Tt;
  unsigned short* Pw = &Pl[w][0];
  int q0 = qt << 6;

  // Q fragments: rows q0+16m+lq, k-halves lh*8 (+32)
  bf16x8 aQ[4][2];
#pragma unroll
  for (int m = 0; m < 4; m++) {
    const unsigned short* qp = Qh + (size_t)(q0 + (m << 4) + lq) * 64 + (lh << 3);
    aQ[m][0] = *(const bf16x8*)(qp);
    aQ[m][1] = *(const bf16x8*)(qp + 32);
  }

  f32x4 zero = {0.f, 0.f, 0.f, 0.f};
  f32x4 acc[4][4];
  float ls[4][4];
#pragma unroll
  for (int m = 0; m < 4; m++)
#pragma unroll
    for (int n = 0; n < 4; n++) acc[m][n] = zero;
#pragma unroll
  for (int m = 0; m < 4; m++)
#pragma unroll
    for (int r = 0; r < 4; r++) ls[m][r] = 0.f;

  bf16x8 kc[4][2];
  int t = w;
  if (t <= qt) {
    int kv0 = t << 6;
#pragma unroll
    for (int n = 0; n < 4; n++) {
      const unsigned short* kp = Kh + (size_t)(kv0 + (n << 4) + lq) * 64 + (lh << 3);
      kc[n][0] = *(const bf16x8*)(kp);
      kc[n][1] = *(const bf16x8*)(kp + 32);
    }
  }

  for (; t <= qt; t += 4) {
    int kv0 = t << 6;
    bool diag = (t == qt);
    bool more = (t + 4 <= qt);

    // V fragments for THIS tile issued early (consumed only after exp+LDS)
    bf16x8 bv[4][2];
#pragma unroll
    for (int n = 0; n < 4; n++) {
      const unsigned short* vp = Vh + (size_t)((n << 4) + lq) * Tt + kv0 + (lh << 3);
      bv[n][0] = *(const bf16x8*)(vp);
      bv[n][1] = *(const bf16x8*)(vp + 32);
    }

    // QK^T for all 16 fragments, exp, write P to LDS
#pragma unroll
    for (int n = 0; n < 4; n++) {
#pragma unroll
      for (int m = 0; m < 4; m++) {
        f32x4 s = zero;
        s = MFMA(aQ[m][0], kc[n][0], s);
        s = MFMA(aQ[m][1], kc[n][1], s);
        if (diag) {
#pragma unroll
          for (int r = 0; r < 4; r++)
            if ((n << 4) + lq > (m << 4) + (lh << 2) + r) s[r] = -1e30f;
        }
#pragma unroll
        for (int r = 0; r < 4; r++) {
          float p = __expf(s[r]);
          ls[m][r] += p;
          Pw[((m << 4) + (lh << 2) + r) * 72 + (n << 4) + lq] = f2b(p);
        }
      }
    }

    // refill K fragments for the wave's next tile (in flight across PV)
    if (more) {
      int kv1 = kv0 + 256;
#pragma unroll
      for (int n = 0; n < 4; n++) {
        const unsigned short* kp = Kh + (size_t)(kv1 + (n << 4) + lq) * 64 + (lh << 3);
        kc[n][0] = *(const bf16x8*)(kp);
        kc[n][1] = *(const bf16x8*)(kp + 32);
      }
    }

    asm volatile("" ::: "memory");  // order P writes before P reads (cross-lane via LDS)

    // PV: O[64q][64hd] += P @ V
#pragma unroll
    for (int ks = 0; ks < 2; ks++) {
      bf16x8 aP[4];
#pragma unroll
      for (int m = 0; m < 4; m++)
        aP[m] = *(const bf16x8*)(Pw + ((m << 4) + lq) * 72 + (ks << 5) + (lh << 3));
#pragma unroll
      for (int n = 0; n < 4; n++) {
#pragma unroll
        for (int m = 0; m < 4; m++) acc[m][n] = MFMA(aP[m], bv[n][ks], acc[m][n]);
      }
    }
    asm volatile("" ::: "memory");  // order P reads before next iteration's writes
  }

  __syncthreads();
  // ---- combine partials across waves ----
  float* Of = (float*)&Pl[0][0];   // [64][65]
  float* Ls = Of + 64 * 65;        // [64]
  for (int i = tid; i < 64 * 65 + 64; i += 256) Of[i] = 0.f;
  __syncthreads();

#pragma unroll
  for (int m = 0; m < 4; m++) {
#pragma unroll
    for (int r = 0; r < 4; r++) {
      float s = ls[m][r];
      s += __shfl_xor(s, 1);
      s += __shfl_xor(s, 2);
      s += __shfl_xor(s, 4);
      s += __shfl_xor(s, 8);
      if (lq == 0) atomicAdd(&Ls[(m << 4) + (lh << 2) + r], s);
    }
  }
#pragma unroll
  for (int m = 0; m < 4; m++)
#pragma unroll
    for (int n = 0; n < 4; n++)
#pragma unroll
      for (int r = 0; r < 4; r++)
        atomicAdd(&Of[((m << 4) + (lh << 2) + r) * 65 + (n << 4) + lq], acc[m][n][r]);
  __syncthreads();

  // ---- write out: thread -> (row = tid>>2, 16 cols) ----
  int row = tid >> 2, cg = (tid & 3) << 4;
  float inv = 1.0f / Ls[row];
  const float* Or = Of + row * 65 + cg;
  uint32_t pk[8];
#pragma unroll
  for (int j = 0; j < 8; j++) {
    pk[j] = f2b(Or[2 * j] * inv) | ((uint32_t)f2b(Or[2 * j + 1] * inv) << 16);
  }
  int bb = bh >> 4, hh = bh & 15;
  unsigned short* yp = yb + ((size_t)(bb * Tt + q0 + row)) * Dd + (hh << 6) + cg;
  uint4 o0 = {pk[0], pk[1], pk[2], pk[3]};
  uint4 o1 = {pk[4], pk[5], pk[6], pk[7]};
  *(uint4*)(yp) = o0;
  *(uint4*)(yp + 8) = o1;
}

extern "C" void kernel_launch(void* const* d_in, const int* in_sizes, int n_in,
                              void* d_out, int out_size, void* d_ws, size_t ws_size,
                              hipStream_t stream) {
  const float* x = (const float*)d_in[0];
  const float* Wk = (const float*)d_in[1];
  const float* bk = (const float*)d_in[2];
  const float* Wq = (const float*)d_in[3];
  const float* bq = (const float*)d_in[4];
  const float* Wv = (const float*)d_in[5];
  const float* bv = (const float*)d_in[6];
  const float* Wp = (const float*)d_in[7];
  const float* bp = (const float*)d_in[8];
  float* out = (float*)d_out;

  char* ws = (char*)d_ws;
  unsigned short* xb  = (unsigned short*)(ws);                       // 16MB
  unsigned short* WkT = (unsigned short*)(ws + (16ull << 20));       // 2MB each
  unsigned short* WqT = (unsigned short*)(ws + (18ull << 20));
  unsigned short* WvT = (unsigned short*)(ws + (20ull << 20));
  unsigned short* WpT = (unsigned short*)(ws + (22ull << 20));
  unsigned short* Qb  = (unsigned short*)(ws + (24ull << 20));       // 16MB
  unsigned short* Kb  = (unsigned short*)(ws + (40ull << 20));       // 16MB
  unsigned short* VTb = (unsigned short*)(ws + (56ull << 20));       // 16MB
  unsigned short* yb  = (unsigned short*)(ws + (72ull << 20));       // 16MB (ends 88MB)

  k_convert_x<<<4096, 256, 0, stream>>>(x, xb);
  k_transpose_w<<<dim3(1024, 4), 256, 0, stream>>>(Wk, Wq, Wv, Wp, WkT, WqT, WvT, WpT);
  k_gemm<<<dim3(64, 24), 256, 0, stream>>>(xb, WqT, WkT, WvT, bq, bk, bv,
                                           Qb, Kb, VTb, nullptr, 1);
  k_attn<<<2048, 256, 0, stream>>>(Qb, Kb, VTb, yb);
  k_gemm<<<dim3(64, 8), 256, 0, stream>>>(yb, WpT, nullptr, nullptr, bp, nullptr, nullptr,
                                          nullptr, nullptr, nullptr, out, 0);
}

// Round 4
// 250.647 us; speedup vs baseline: 2.2380x; 1.8368x over previous
//
#include <hip/hip_runtime.h>
#include <stdint.h>

#define Bb 4
#define Tt 2048
#define Dd 1024
#define Hh 16
#define HDd 64
#define Mm 8192   // Bb*Tt

typedef __attribute__((ext_vector_type(8))) short bf16x8;
typedef __attribute__((ext_vector_type(4))) float f32x4;
typedef __attribute__((ext_vector_type(16))) float f32x16;

#define MFMA(a, b, c) __builtin_amdgcn_mfma_f32_16x16x32_bf16(a, b, c, 0, 0, 0)
#define MFMA32(a, b, c) __builtin_amdgcn_mfma_f32_32x32x16_bf16(a, b, c, 0, 0, 0)

__device__ __forceinline__ unsigned short f2b(float f) {
  union { float f; uint32_t u; } v; v.f = f;
  return (unsigned short)((v.u + 0x7FFFu + ((v.u >> 16) & 1u)) >> 16);
}

__device__ __forceinline__ void gload_lds16(const void* g, void* l) {
  __builtin_amdgcn_global_load_lds(
      (const __attribute__((address_space(1))) void*)g,
      (__attribute__((address_space(3))) void*)l, 16, 0, 0);
}

// ---------------- x f32 -> bf16 ----------------
__global__ __launch_bounds__(256) void k_convert_x(const float* __restrict__ x,
                                                   unsigned short* __restrict__ xb) {
  int i = (blockIdx.x * 256 + threadIdx.x) * 8;
  float4 a = *(const float4*)(x + i);
  float4 b = *(const float4*)(x + i + 4);
  uint4 o;
  o.x = f2b(a.x) | ((uint32_t)f2b(a.y) << 16);
  o.y = f2b(a.z) | ((uint32_t)f2b(a.w) << 16);
  o.z = f2b(b.x) | ((uint32_t)f2b(b.y) << 16);
  o.w = f2b(b.z) | ((uint32_t)f2b(b.w) << 16);
  *(uint4*)(xb + i) = o;
}

// ---------------- W [K][N] f32 -> Wt [N][K] bf16 ----------------
__global__ __launch_bounds__(256) void k_transpose_w(
    const float* __restrict__ Wk, const float* __restrict__ Wq,
    const float* __restrict__ Wv, const float* __restrict__ Wp,
    unsigned short* __restrict__ WkT, unsigned short* __restrict__ WqT,
    unsigned short* __restrict__ WvT, unsigned short* __restrict__ WpT) {
  const float* W; unsigned short* O;
  int wsel = blockIdx.y;
  W = wsel == 0 ? Wk : wsel == 1 ? Wq : wsel == 2 ? Wv : Wp;
  O = wsel == 0 ? WkT : wsel == 1 ? WqT : wsel == 2 ? WvT : WpT;
  __shared__ unsigned short tile[32][36];
  int kb = (blockIdx.x >> 5) << 5;
  int nb = (blockIdx.x & 31) << 5;
  int t = threadIdx.x;
  int r = t >> 3, c4 = (t & 7) << 2;
  float4 v = *(const float4*)(W + (size_t)(kb + r) * Dd + nb + c4);
  tile[r][c4 + 0] = f2b(v.x); tile[r][c4 + 1] = f2b(v.y);
  tile[r][c4 + 2] = f2b(v.z); tile[r][c4 + 3] = f2b(v.w);
  __syncthreads();
  uint2 o;
  o.x = tile[c4 + 0][r] | ((uint32_t)tile[c4 + 1][r] << 16);
  o.y = tile[c4 + 2][r] | ((uint32_t)tile[c4 + 3][r] << 16);
  *(uint2*)(O + (size_t)(nb + r) * Dd + kb + c4) = o;
}

// ---------------- GEMM: A[M][1024] bf16 @ Bt[N][1024]^T + bias ----------------
// qkv=1: Q,K -> [B,H,T,64] (K row-swizzled), V -> [B,H,64,T] (t-swizzled)
// qkv=0: f32 out [M][1024]
__global__ __launch_bounds__(256) void k_gemm(
    const unsigned short* __restrict__ A,
    const unsigned short* __restrict__ Bt0, const unsigned short* __restrict__ Bt1,
    const unsigned short* __restrict__ Bt2,
    const float* __restrict__ bias0, const float* __restrict__ bias1,
    const float* __restrict__ bias2,
    unsigned short* __restrict__ Qb, unsigned short* __restrict__ Kb,
    unsigned short* __restrict__ VTb, float* __restrict__ Pout, int qkv) {
  __shared__ __align__(16) unsigned short Al[128 * 32];
  __shared__ __align__(16) unsigned short Bl[128 * 32];
  int tid = threadIdx.x;
  int lane = tid & 63, wid = tid >> 6;
  int wr = wid >> 1, wc = wid & 1;
  int lq = lane & 15, lh = lane >> 4;
  int mb = blockIdx.x * 128;
  int by = blockIdx.y;
  int widx, nb;
  const unsigned short* Bt; const float* bias;
  if (qkv) {
    widx = by >> 3; nb = (by & 7) << 7;
    Bt = widx == 0 ? Bt0 : (widx == 1 ? Bt1 : Bt2);
    bias = widx == 0 ? bias0 : (widx == 1 ? bias1 : bias2);
  } else {
    widx = 3; nb = by << 7; Bt = Bt0; bias = bias0;
  }

  int srow = (wid << 5) + (lane >> 2);
  int scol = (lane & 3) << 3;
  const unsigned short* Ag = A + (size_t)(mb + srow) * Dd + scol;
  const unsigned short* Bg = Bt + (size_t)(nb + srow) * Dd + scol;
  unsigned short* Alw = Al + (wid << 10);
  unsigned short* Blw = Bl + (wid << 10);

  f32x4 zero = {0.f, 0.f, 0.f, 0.f};
  f32x4 acc[4][4];
#pragma unroll
  for (int m = 0; m < 4; m++)
#pragma unroll
    for (int n = 0; n < 4; n++) acc[m][n] = zero;

  for (int kb = 0; kb < Dd; kb += 32) {
    __syncthreads();
    gload_lds16(Ag + kb, Alw);
    gload_lds16(Ag + kb + 16 * Dd, Alw + 16 * 32);
    gload_lds16(Bg + kb, Blw);
    gload_lds16(Bg + kb + 16 * Dd, Blw + 16 * 32);
    __syncthreads();
    bf16x8 af[4], bf[4];
#pragma unroll
    for (int m = 0; m < 4; m++)
      af[m] = *(const bf16x8*)(Al + (((wr << 6) + (m << 4) + lq) << 5) + (lh << 3));
#pragma unroll
    for (int n = 0; n < 4; n++)
      bf[n] = *(const bf16x8*)(Bl + (((wc << 6) + (n << 4) + lq) << 5) + (lh << 3));
#pragma unroll
    for (int m = 0; m < 4; m++)
#pragma unroll
      for (int n = 0; n < 4; n++) acc[m][n] = MFMA(af[m], bf[n], acc[m][n]);
  }

  int b_idx = mb >> 11;
#pragma unroll
  for (int n = 0; n < 4; n++) {
    int col = nb + (wc << 6) + (n << 4) + lq;
    float bb = bias[col];
    int hh = col >> 6, hd = col & 63;
#pragma unroll
    for (int m = 0; m < 4; m++) {
      int row0 = mb + (wr << 6) + (m << 4) + (lh << 2);
      int t0 = row0 & 2047;
      if (widx == 3) {
#pragma unroll
        for (int r = 0; r < 4; r++)
          Pout[(size_t)(row0 + r) * Dd + col] = acc[m][n][r] + bb;
      } else if (widx == 2) {
        float v0 = acc[m][n][0] + bb, v1 = acc[m][n][1] + bb;
        float v2 = acc[m][n][2] + bb, v3 = acc[m][n][3] + bb;
        uint2 pv;
        pv.x = f2b(v0) | ((uint32_t)f2b(v1) << 16);
        pv.y = f2b(v2) | ((uint32_t)f2b(v3) << 16);
        int t0s = t0 ^ ((hd & 7) << 3);  // V swizzle: t 16B-block ^= hd&7
        *(uint2*)(VTb + ((size_t)(b_idx * 16 + hh) * 64 + hd) * Tt + t0s) = pv;
      } else {
        unsigned short* O = (widx == 0) ? Qb : Kb;
        float sc = (widx == 0) ? 0.125f : 1.0f;
#pragma unroll
        for (int r = 0; r < 4; r++) {
          float v = (acc[m][n][r] + bb) * sc;
          int trow = t0 + r;
          int hds = (widx == 0) ? hd : (hd ^ ((trow & 7) << 3));  // K swizzle
          O[((size_t)(b_idx * 16 + hh) * Tt + trow) * 64 + hds] = f2b(v);
        }
      }
    }
  }
}

// ---------------- flash attention (causal), Q pre-scaled ----------------
// block = 128 q rows, 4 waves each owning 32 q rows. K/V staged to LDS via
// global_load_lds (double buffer, stage(jt+1) before compute(jt)).
// Swapped QK^T (mfma(K,Q)); P goes through a per-wave padded LDS buffer
// (validated round-1/2 technique) instead of cvt_pk/permlane (round-3 suspect).
__global__ __launch_bounds__(256) void k_attn(
    const unsigned short* __restrict__ Qb, const unsigned short* __restrict__ Kb,
    const unsigned short* __restrict__ VTb, unsigned short* __restrict__ yb) {
  __shared__ __align__(16) unsigned short KL[2][4096];
  __shared__ __align__(16) unsigned short VL[2][4096];
  __shared__ __align__(16) unsigned short Pl[4][32 * 72];  // per-wave P, stride 72
  int blk = blockIdx.x;
  int bh = blk >> 4;
  int qb = 15 - (blk & 15);   // heavy blocks first
  int q0 = qb << 7;
  int tid = threadIdx.x, lane = tid & 63, w = tid >> 6;
  int l31 = lane & 31, hi = lane >> 5;
  const unsigned short* __restrict__ Qh = Qb + (size_t)bh * Tt * 64;
  const unsigned short* __restrict__ Kh = Kb + (size_t)bh * Tt * 64;
  const unsigned short* __restrict__ Vh = VTb + (size_t)bh * 64 * Tt;
  unsigned short* Pw = &Pl[w][0];
  int qg = q0 + (w << 5);

  // Q B-fragments: lane holds Q[qg+l31][16c + 8hi + j]
  bf16x8 qf[4];
#pragma unroll
  for (int c = 0; c < 4; c++)
    qf[c] = *(const bf16x8*)(Qh + (size_t)(qg + l31) * 64 + (c << 4) + (hi << 3));

  f32x16 acc0, acc1;
#pragma unroll
  for (int i = 0; i < 16; i++) { acc0[i] = 0.f; acc1[i] = 0.f; }
  float lsum = 0.f;

  int jmax = (q0 >> 6) + 1;
  int srow = lane >> 3;        // 0..7
  int scol = (lane & 7) << 3;  // shorts

  // prologue: stage tile 0 into buf 0
#pragma unroll
  for (int i = 0; i < 2; i++) {
    int row = (w << 4) + (i << 3);
    gload_lds16(Kh + (size_t)(row + srow) * 64 + scol, &KL[0][row << 6]);
    gload_lds16(Vh + (size_t)(row + srow) * Tt + scol, &VL[0][row << 6]);
  }
  __syncthreads();

  int cur = 0;
  for (int jt = 0; jt <= jmax; ++jt) {
    if (jt < jmax) {  // stage next tile into the other buffer
      int kv1 = (jt + 1) << 6;
#pragma unroll
      for (int i = 0; i < 2; i++) {
        int row = (w << 4) + (i << 3);
        gload_lds16(Kh + (size_t)(kv1 + row + srow) * 64 + scol, &KL[cur ^ 1][row << 6]);
        gload_lds16(Vh + (size_t)(row + srow) * Tt + kv1 + scol, &VL[cur ^ 1][row << 6]);
      }
    }
    int kv0 = jt << 6;
    int d = qg - kv0;   // wave-uniform
    if (d >= 0) {
      const unsigned short* KB = &KL[cur][0];
      const unsigned short* VB = &VL[cur][0];
      bf16x8 kf[2][4], vf[2][4];
#pragma unroll
      for (int n2 = 0; n2 < 2; n2++)
#pragma unroll
        for (int c = 0; c < 4; c++) {
          int row = (n2 << 5) + l31;
          int cb = ((((c << 1) + hi) ^ (row & 7)) << 3);
          kf[n2][c] = *(const bf16x8*)(KB + (row << 6) + cb);
          vf[n2][c] = *(const bf16x8*)(VB + (row << 6) + cb);
        }
      bool diag = (d < 64);
      int rel = d + l31;
#pragma unroll
      for (int n2 = 0; n2 < 2; n2++) {
        f32x16 s;
#pragma unroll
        for (int i = 0; i < 16; i++) s[i] = 0.f;
#pragma unroll
        for (int c = 0; c < 4; c++) s = MFMA32(kf[n2][c], qf[c], s);
        float p[16];
#pragma unroll
        for (int r = 0; r < 16; r++) {
          float sv = s[r];
          if (diag) {
            int krow = (n2 << 5) + (r & 3) + ((r >> 2) << 3) + (hi << 2);
            sv = (krow > rel) ? -1e30f : sv;
          }
          p[r] = __expf(sv);
        }
        lsum += (((p[0] + p[1]) + (p[2] + p[3])) + ((p[4] + p[5]) + (p[6] + p[7])))
              + (((p[8] + p[9]) + (p[10] + p[11])) + ((p[12] + p[13]) + (p[14] + p[15])));
        // P[q=l31][kv = 32*n2 + 8g + 4hi + i] = p[4g+i]  (crow layout, b64 packs)
#pragma unroll
        for (int g = 0; g < 4; g++) {
          uint2 pw;
          pw.x = f2b(p[4 * g + 0]) | ((uint32_t)f2b(p[4 * g + 1]) << 16);
          pw.y = f2b(p[4 * g + 2]) | ((uint32_t)f2b(p[4 * g + 3]) << 16);
          *(uint2*)(Pw + l31 * 72 + (n2 << 5) + (g << 3) + (hi << 2)) = pw;
        }
      }
      asm volatile("" ::: "memory");  // order P writes before cross-lane P reads
      // PV: A-fragment aP[c][j] = P[l31][16c + 8hi + j]
#pragma unroll
      for (int c = 0; c < 4; c++) {
        bf16x8 aP = *(const bf16x8*)(Pw + l31 * 72 + (c << 4) + (hi << 3));
        acc0 = MFMA32(aP, vf[0][c], acc0);
        acc1 = MFMA32(aP, vf[1][c], acc1);
      }
      asm volatile("" ::: "memory");  // order P reads before next tile's writes
    }
    __syncthreads();
    cur ^= 1;
  }

  lsum += __shfl_xor(lsum, 32);
  float inv = 1.0f / lsum;
  int bb = bh >> 4, hh = bh & 15;
#pragma unroll
  for (int r = 0; r < 16; r++) {
    int qr = (r & 3) + ((r >> 2) << 3) + (hi << 2);
    float invq = __shfl(inv, qr);
    size_t base = ((size_t)(bb * Tt + qg + qr)) * Dd + (hh << 6) + l31;
    yb[base] = f2b(acc0[r] * invq);
    yb[base + 32] = f2b(acc1[r] * invq);
  }
}

extern "C" void kernel_launch(void* const* d_in, const int* in_sizes, int n_in,
                              void* d_out, int out_size, void* d_ws, size_t ws_size,
                              hipStream_t stream) {
  const float* x = (const float*)d_in[0];
  const float* Wk = (const float*)d_in[1];
  const float* bk = (const float*)d_in[2];
  const float* Wq = (const float*)d_in[3];
  const float* bq = (const float*)d_in[4];
  const float* Wv = (const float*)d_in[5];
  const float* bv = (const float*)d_in[6];
  const float* Wp = (const float*)d_in[7];
  const float* bp = (const float*)d_in[8];
  float* out = (float*)d_out;

  char* ws = (char*)d_ws;
  unsigned short* xb  = (unsigned short*)(ws);                       // 16MB
  unsigned short* WkT = (unsigned short*)(ws + (16ull << 20));       // 2MB each
  unsigned short* WqT = (unsigned short*)(ws + (18ull << 20));
  unsigned short* WvT = (unsigned short*)(ws + (20ull << 20));
  unsigned short* WpT = (unsigned short*)(ws + (22ull << 20));
  unsigned short* Qb  = (unsigned short*)(ws + (24ull << 20));       // 16MB
  unsigned short* Kb  = (unsigned short*)(ws + (40ull << 20));       // 16MB
  unsigned short* VTb = (unsigned short*)(ws + (56ull << 20));       // 16MB
  unsigned short* yb  = (unsigned short*)(ws + (72ull << 20));       // 16MB (ends 88MB)

  k_convert_x<<<4096, 256, 0, stream>>>(x, xb);
  k_transpose_w<<<dim3(1024, 4), 256, 0, stream>>>(Wk, Wq, Wv, Wp, WkT, WqT, WvT, WpT);
  k_gemm<<<dim3(64, 24), 256, 0, stream>>>(xb, WqT, WkT, WvT, bq, bk, bv,
                                           Qb, Kb, VTb, nullptr, 1);
  k_attn<<<1024, 256, 0, stream>>>(Qb, Kb, VTb, yb);
  k_gemm<<<dim3(64, 8), 256, 0, stream>>>(yb, WpT, nullptr, nullptr, bp, nullptr, nullptr,
                                          nullptr, nullptr, nullptr, out, 0);
}

// Round 5
// 207.246 us; speedup vs baseline: 2.7067x; 1.2094x over previous
//
#include <hip/hip_runtime.h>
#include <stdint.h>

#define Bb 4
#define Tt 2048
#define Dd 1024
#define Hh 16
#define HDd 64
#define Mm 8192   // Bb*Tt

typedef __attribute__((ext_vector_type(8))) short bf16x8;
typedef __attribute__((ext_vector_type(4))) float f32x4;
typedef __attribute__((ext_vector_type(16))) float f32x16;

#define MFMA(a, b, c) __builtin_amdgcn_mfma_f32_16x16x32_bf16(a, b, c, 0, 0, 0)
#define MFMA32(a, b, c) __builtin_amdgcn_mfma_f32_32x32x16_bf16(a, b, c, 0, 0, 0)

__device__ __forceinline__ unsigned short f2b(float f) {
  union { float f; uint32_t u; } v; v.f = f;
  return (unsigned short)((v.u + 0x7FFFu + ((v.u >> 16) & 1u)) >> 16);
}

__device__ __forceinline__ void gload_lds16(const void* g, void* l) {
  __builtin_amdgcn_global_load_lds(
      (const __attribute__((address_space(1))) void*)g,
      (__attribute__((address_space(3))) void*)l, 16, 0, 0);
}

// ---------------- x f32 -> bf16 ----------------
__global__ __launch_bounds__(256) void k_convert_x(const float* __restrict__ x,
                                                   unsigned short* __restrict__ xb) {
  int i = (blockIdx.x * 256 + threadIdx.x) * 8;
  float4 a = *(const float4*)(x + i);
  float4 b = *(const float4*)(x + i + 4);
  uint4 o;
  o.x = f2b(a.x) | ((uint32_t)f2b(a.y) << 16);
  o.y = f2b(a.z) | ((uint32_t)f2b(a.w) << 16);
  o.z = f2b(b.x) | ((uint32_t)f2b(b.y) << 16);
  o.w = f2b(b.z) | ((uint32_t)f2b(b.w) << 16);
  *(uint4*)(xb + i) = o;
}

// ---------------- W [K][N] f32 -> Wt [N][K] bf16 ----------------
__global__ __launch_bounds__(256) void k_transpose_w(
    const float* __restrict__ Wk, const float* __restrict__ Wq,
    const float* __restrict__ Wv, const float* __restrict__ Wp,
    unsigned short* __restrict__ WkT, unsigned short* __restrict__ WqT,
    unsigned short* __restrict__ WvT, unsigned short* __restrict__ WpT) {
  const float* W; unsigned short* O;
  int wsel = blockIdx.y;
  W = wsel == 0 ? Wk : wsel == 1 ? Wq : wsel == 2 ? Wv : Wp;
  O = wsel == 0 ? WkT : wsel == 1 ? WqT : wsel == 2 ? WvT : WpT;
  __shared__ unsigned short tile[32][36];
  int kb = (blockIdx.x >> 5) << 5;
  int nb = (blockIdx.x & 31) << 5;
  int t = threadIdx.x;
  int r = t >> 3, c4 = (t & 7) << 2;
  float4 v = *(const float4*)(W + (size_t)(kb + r) * Dd + nb + c4);
  tile[r][c4 + 0] = f2b(v.x); tile[r][c4 + 1] = f2b(v.y);
  tile[r][c4 + 2] = f2b(v.z); tile[r][c4 + 3] = f2b(v.w);
  __syncthreads();
  uint2 o;
  o.x = tile[c4 + 0][r] | ((uint32_t)tile[c4 + 1][r] << 16);
  o.y = tile[c4 + 2][r] | ((uint32_t)tile[c4 + 3][r] << 16);
  *(uint2*)(O + (size_t)(nb + r) * Dd + kb + c4) = o;
}

// ---------------- GEMM: A[M][1024] bf16 @ Bt[N][1024]^T + bias ----------------
// qkv=1: Q,K -> [B,H,T,64] (K row-swizzled), V -> [B,H,64,T] (t-swizzled)
// qkv=0: f32 out [M][1024]
__global__ __launch_bounds__(256) void k_gemm(
    const unsigned short* __restrict__ A,
    const unsigned short* __restrict__ Bt0, const unsigned short* __restrict__ Bt1,
    const unsigned short* __restrict__ Bt2,
    const float* __restrict__ bias0, const float* __restrict__ bias1,
    const float* __restrict__ bias2,
    unsigned short* __restrict__ Qb, unsigned short* __restrict__ Kb,
    unsigned short* __restrict__ VTb, float* __restrict__ Pout, int qkv) {
  __shared__ __align__(16) unsigned short Al[128 * 32];
  __shared__ __align__(16) unsigned short Bl[128 * 32];
  int tid = threadIdx.x;
  int lane = tid & 63, wid = tid >> 6;
  int wr = wid >> 1, wc = wid & 1;
  int lq = lane & 15, lh = lane >> 4;
  int mb = blockIdx.x * 128;
  int by = blockIdx.y;
  int widx, nb;
  const unsigned short* Bt; const float* bias;
  if (qkv) {
    widx = by >> 3; nb = (by & 7) << 7;
    Bt = widx == 0 ? Bt0 : (widx == 1 ? Bt1 : Bt2);
    bias = widx == 0 ? bias0 : (widx == 1 ? bias1 : bias2);
  } else {
    widx = 3; nb = by << 7; Bt = Bt0; bias = bias0;
  }

  int srow = (wid << 5) + (lane >> 2);
  int scol = (lane & 3) << 3;
  const unsigned short* Ag = A + (size_t)(mb + srow) * Dd + scol;
  const unsigned short* Bg = Bt + (size_t)(nb + srow) * Dd + scol;
  unsigned short* Alw = Al + (wid << 10);
  unsigned short* Blw = Bl + (wid << 10);

  f32x4 zero = {0.f, 0.f, 0.f, 0.f};
  f32x4 acc[4][4];
#pragma unroll
  for (int m = 0; m < 4; m++)
#pragma unroll
    for (int n = 0; n < 4; n++) acc[m][n] = zero;

  for (int kb = 0; kb < Dd; kb += 32) {
    __syncthreads();
    gload_lds16(Ag + kb, Alw);
    gload_lds16(Ag + kb + 16 * Dd, Alw + 16 * 32);
    gload_lds16(Bg + kb, Blw);
    gload_lds16(Bg + kb + 16 * Dd, Blw + 16 * 32);
    __syncthreads();
    bf16x8 af[4], bf[4];
#pragma unroll
    for (int m = 0; m < 4; m++)
      af[m] = *(const bf16x8*)(Al + (((wr << 6) + (m << 4) + lq) << 5) + (lh << 3));
#pragma unroll
    for (int n = 0; n < 4; n++)
      bf[n] = *(const bf16x8*)(Bl + (((wc << 6) + (n << 4) + lq) << 5) + (lh << 3));
#pragma unroll
    for (int m = 0; m < 4; m++)
#pragma unroll
      for (int n = 0; n < 4; n++) acc[m][n] = MFMA(af[m], bf[n], acc[m][n]);
  }

  int b_idx = mb >> 11;
#pragma unroll
  for (int n = 0; n < 4; n++) {
    int col = nb + (wc << 6) + (n << 4) + lq;
    float bb = bias[col];
    int hh = col >> 6, hd = col & 63;
#pragma unroll
    for (int m = 0; m < 4; m++) {
      int row0 = mb + (wr << 6) + (m << 4) + (lh << 2);
      int t0 = row0 & 2047;
      if (widx == 3) {
#pragma unroll
        for (int r = 0; r < 4; r++)
          Pout[(size_t)(row0 + r) * Dd + col] = acc[m][n][r] + bb;
      } else if (widx == 2) {
        float v0 = acc[m][n][0] + bb, v1 = acc[m][n][1] + bb;
        float v2 = acc[m][n][2] + bb, v3 = acc[m][n][3] + bb;
        uint2 pv;
        pv.x = f2b(v0) | ((uint32_t)f2b(v1) << 16);
        pv.y = f2b(v2) | ((uint32_t)f2b(v3) << 16);
        int t0s = t0 ^ ((hd & 7) << 3);  // V swizzle: t 16B-block ^= hd&7
        *(uint2*)(VTb + ((size_t)(b_idx * 16 + hh) * 64 + hd) * Tt + t0s) = pv;
      } else {
        unsigned short* O = (widx == 0) ? Qb : Kb;
        float sc = (widx == 0) ? 0.125f : 1.0f;
#pragma unroll
        for (int r = 0; r < 4; r++) {
          float v = (acc[m][n][r] + bb) * sc;
          int trow = t0 + r;
          int hds = (widx == 0) ? hd : (hd ^ ((trow & 7) << 3));  // K swizzle
          O[((size_t)(b_idx * 16 + hh) * Tt + trow) * 64 + hds] = f2b(v);
        }
      }
    }
  }
}

// ---------------- flash attention (causal), Q pre-scaled ----------------
// block = 512 threads (8 waves); waves 0-3 own q-group a (128 rows),
// waves 4-7 own q-group 15-a => per-block work is uniform across the grid.
// K/V staged via global_load_lds (double buffer). Swapped QK^T; P stays
// in registers: V B-fragment assembled from 2x b64 LDS reads whose kv rows
// match the C/D slot order, so raw exp'd values pack directly (no permlane,
// no LDS P buffer).
__global__ __launch_bounds__(512, 4) void k_attn(
    const unsigned short* __restrict__ Qb, const unsigned short* __restrict__ Kb,
    const unsigned short* __restrict__ VTb, unsigned short* __restrict__ yb) {
  __shared__ __align__(16) unsigned short KL[2][4096];
  __shared__ __align__(16) unsigned short VL[2][4096];
  int blk = blockIdx.x;
  int bh = blk >> 3;
  int a = blk & 7;                  // pair (a, 15-a)
  int tid = threadIdx.x, lane = tid & 63, w = tid >> 6;
  int l31 = lane & 31, hi = lane >> 5;
  const unsigned short* __restrict__ Qh = Qb + (size_t)bh * Tt * 64;
  const unsigned short* __restrict__ Kh = Kb + (size_t)bh * Tt * 64;
  const unsigned short* __restrict__ Vh = VTb + (size_t)bh * 64 * Tt;
  int qgrp = (w < 4) ? a : (15 - a);
  int qg = (qgrp << 7) + ((w & 3) << 5);

  // Q B-fragments: lane holds Q[qg+l31][16c + 8hi + j]
  bf16x8 qf[4];
#pragma unroll
  for (int c = 0; c < 4; c++)
    qf[c] = *(const bf16x8*)(Qh + (size_t)(qg + l31) * 64 + (c << 4) + (hi << 3));

  f32x16 acc0, acc1;
#pragma unroll
  for (int i = 0; i < 16; i++) { acc0[i] = 0.f; acc1[i] = 0.f; }
  float lsum = 0.f;

  int jmax = 31 - 2 * a;            // covers the larger group (15-a)
  int srow = lane >> 3;             // 0..7
  int scol = (lane & 7) << 3;       // shorts
  int rowb = w << 3;                // 8 rows per wave

  // prologue: stage tile 0 into buf 0 (1 K + 1 V gload per wave)
  gload_lds16(Kh + (size_t)(rowb + srow) * 64 + scol, &KL[0][rowb << 6]);
  gload_lds16(Vh + (size_t)(rowb + srow) * Tt + scol, &VL[0][rowb << 6]);
  __syncthreads();

  int cur = 0;
  for (int jt = 0; jt <= jmax; ++jt) {
    if (jt < jmax) {  // stage next tile into the other buffer
      int kv1 = (jt + 1) << 6;
      gload_lds16(Kh + (size_t)(kv1 + rowb + srow) * 64 + scol, &KL[cur ^ 1][rowb << 6]);
      gload_lds16(Vh + (size_t)(rowb + srow) * Tt + kv1 + scol, &VL[cur ^ 1][rowb << 6]);
    }
    int kv0 = jt << 6;
    int d = qg - kv0;   // wave-uniform
    if (d >= 0) {
      const unsigned short* KB = &KL[cur][0];
      const unsigned short* VB = &VL[cur][0];
      bool diag = (d < 64);
      int rel = d + l31;
      int swz = l31 & 7;
#pragma unroll
      for (int n2 = 0; n2 < 2; n2++) {
        // K fragments for this kv-half
        bf16x8 kf[4];
        int krowb = ((n2 << 5) + l31) << 6;
#pragma unroll
        for (int c = 0; c < 4; c++)
          kf[c] = *(const bf16x8*)(KB + krowb + ((((c << 1) + hi) ^ swz) << 3));
        f32x16 s;
#pragma unroll
        for (int i = 0; i < 16; i++) s[i] = 0.f;
#pragma unroll
        for (int c = 0; c < 4; c++) s = MFMA32(kf[c], qf[c], s);
        float p[16];
#pragma unroll
        for (int r = 0; r < 16; r++) {
          float sv = s[r];
          if (diag) {
            int krow = (n2 << 5) + (r & 3) + ((r >> 2) << 3) + (hi << 2);
            sv = (krow > rel) ? -1e30f : sv;
          }
          p[r] = __expf(sv);
        }
        lsum += (((p[0] + p[1]) + (p[2] + p[3])) + ((p[4] + p[5]) + (p[6] + p[7])))
              + (((p[8] + p[9]) + (p[10] + p[11])) + ((p[12] + p[13]) + (p[14] + p[15])));
        // V fragments: element (hi,j) = V[kv0 + 32n2 + 16cc + 8(j>>2)+4hi+(j&3)][hd]
        // = two b64 reads at t 8-blocks (4n2+2cc) and (4n2+2cc+1), offset 4hi
        union { uint2 u2[2]; bf16x8 v; } vf[2][2];
#pragma unroll
        for (int n2v = 0; n2v < 2; n2v++) {
          int vrowb = ((n2v << 5) + l31) << 6;
#pragma unroll
          for (int cc = 0; cc < 2; cc++) {
            int blk0 = (n2 << 2) + (cc << 1);
            vf[n2v][cc].u2[0] =
                *(const uint2*)(VB + vrowb + (((blk0 + 0) ^ swz) << 3) + (hi << 2));
            vf[n2v][cc].u2[1] =
                *(const uint2*)(VB + vrowb + (((blk0 + 1) ^ swz) << 3) + (hi << 2));
          }
        }
        // pack P into A-fragments (register-local, slot order already matches)
        union { uint32_t u[4]; bf16x8 v; } ap0, ap1;
#pragma unroll
        for (int g = 0; g < 4; g++) {
          ap0.u[g] = f2b(p[2 * g]) | ((uint32_t)f2b(p[2 * g + 1]) << 16);
          ap1.u[g] = f2b(p[8 + 2 * g]) | ((uint32_t)f2b(p[8 + 2 * g + 1]) << 16);
        }
        acc0 = MFMA32(ap0.v, vf[0][0].v, acc0);
        acc1 = MFMA32(ap0.v, vf[1][0].v, acc1);
        acc0 = MFMA32(ap1.v, vf[0][1].v, acc0);
        acc1 = MFMA32(ap1.v, vf[1][1].v, acc1);
      }
    }
    __syncthreads();
    cur ^= 1;
  }

  lsum += __shfl_xor(lsum, 32);
  float inv = 1.0f / lsum;
  int bb = bh >> 4, hh = bh & 15;
#pragma unroll
  for (int r = 0; r < 16; r++) {
    int qr = (r & 3) + ((r >> 2) << 3) + (hi << 2);
    float invq = __shfl(inv, qr);
    size_t base = ((size_t)(bb * Tt + qg + qr)) * Dd + (hh << 6) + l31;
    yb[base] = f2b(acc0[r] * invq);
    yb[base + 32] = f2b(acc1[r] * invq);
  }
}

extern "C" void kernel_launch(void* const* d_in, const int* in_sizes, int n_in,
                              void* d_out, int out_size, void* d_ws, size_t ws_size,
                              hipStream_t stream) {
  const float* x = (const float*)d_in[0];
  const float* Wk = (const float*)d_in[1];
  const float* bk = (const float*)d_in[2];
  const float* Wq = (const float*)d_in[3];
  const float* bq = (const float*)d_in[4];
  const float* Wv = (const float*)d_in[5];
  const float* bv = (const float*)d_in[6];
  const float* Wp = (const float*)d_in[7];
  const float* bp = (const float*)d_in[8];
  float* out = (float*)d_out;

  char* ws = (char*)d_ws;
  unsigned short* xb  = (unsigned short*)(ws);                       // 16MB
  unsigned short* WkT = (unsigned short*)(ws + (16ull << 20));       // 2MB each
  unsigned short* WqT = (unsigned short*)(ws + (18ull << 20));
  unsigned short* WvT = (unsigned short*)(ws + (20ull << 20));
  unsigned short* WpT = (unsigned short*)(ws + (22ull << 20));
  unsigned short* Qb  = (unsigned short*)(ws + (24ull << 20));       // 16MB
  unsigned short* Kb  = (unsigned short*)(ws + (40ull << 20));       // 16MB
  unsigned short* VTb = (unsigned short*)(ws + (56ull << 20));       // 16MB
  unsigned short* yb  = (unsigned short*)(ws + (72ull << 20));       // 16MB (ends 88MB)

  k_convert_x<<<4096, 256, 0, stream>>>(x, xb);
  k_transpose_w<<<dim3(1024, 4), 256, 0, stream>>>(Wk, Wq, Wv, Wp, WkT, WqT, WvT, WpT);
  k_gemm<<<dim3(64, 24), 256, 0, stream>>>(xb, WqT, WkT, WvT, bq, bk, bv,
                                           Qb, Kb, VTb, nullptr, 1);
  k_attn<<<512, 512, 0, stream>>>(Qb, Kb, VTb, yb);
  k_gemm<<<dim3(64, 8), 256, 0, stream>>>(yb, WpT, nullptr, nullptr, bp, nullptr, nullptr,
                                          nullptr, nullptr, nullptr, out, 0);
}